// Round 5
// baseline (142.930 us; speedup 1.0000x reference)
//
#include <hip/hip_runtime.h>

#define NC 14
#define DIM 96
#define VOL (96 * 96 * 96)    // 884736
#define VPT 4                  // voxels per thread per iteration
#define TPB 256
#define VPB (VPT * TPB)        // 1024 voxels per chunk
#define NCHUNK (VOL / VPB)     // 864 chunks per batch
#define ITERS 2
#define NBT (NCHUNK / ITERS)   // 432 blocks per batch

__global__ __launch_bounds__(256, 4) void bkd_main(const float* __restrict__ S,
                                                   const float* __restrict__ T,
                                                   const int* __restrict__ L,
                                                   float* __restrict__ partials) {
    const int b = blockIdx.x / NBT;
    const int local = blockIdx.x % NBT;
    const int tid = threadIdx.x;

    const float* Sbase = S + (size_t)b * NC * VOL;
    const float* Tbase = T + (size_t)b * NC * VOL;
    const int* lab = L + b * VOL;

    float acc_sum[NC];
    unsigned cntpk[7];   // class k count in 16-bit field (k&1) of word k>>1
#pragma unroll
    for (int k = 0; k < NC; ++k) acc_sum[k] = 0.f;
#pragma unroll
    for (int j = 0; j < 7; ++j) cntpk[j] = 0u;

#pragma unroll
    for (int it = 0; it < ITERS; ++it) {
        const int v0 = (ITERS * local + it) * VPB + tid * VPT;  // multiple of 4
        const int d0 = v0 % DIM;
        const int w = (v0 / DIM) % DIM;
        const int h = v0 / (DIM * DIM);
        const bool has_lo = (d0 > 0);
        const bool has_hi = (d0 + VPT < DIM);

        // ---------------- issue LABEL loads first (consumed first) ------------
        int4 q[9];
        int plo[9], phi[9];
        bool cvalid[9];
#pragma unroll
        for (int dh = -1; dh <= 1; ++dh) {
#pragma unroll
            for (int dw = -1; dw <= 1; ++dw) {
                const int ci = (dh + 1) * 3 + (dw + 1);
                const int h2 = h + dh, w2 = w + dw;
                const bool ok = ((unsigned)h2 < DIM) & ((unsigned)w2 < DIM);
                cvalid[ci] = ok;
                const int* p = lab + (h2 * DIM + w2) * DIM + d0;
                if (ok) {
                    q[ci] = *(const int4*)p;
                    plo[ci] = has_lo ? p[-1] : 0;
                    phi[ci] = has_hi ? p[4] : 0;
                }
            }
        }

        // ---------------- issue ALL 28 class float4 loads ---------------------
        const float* Sb = Sbase + v0;
        const float* Tb = Tbase + v0;
        float4 sv[NC], tv[NC];
#pragma unroll
        for (int c = 0; c < NC; ++c) {
            sv[c] = *(const float4*)(Sb + c * VOL);
            tv[c] = *(const float4*)(Tb + c * VOL);
        }

        // ---------------- boundary masks (VALU under class-load latency) ------
        unsigned vmask[VPT] = {0u, 0u, 0u, 0u};
#pragma unroll
        for (int ci = 0; ci < 9; ++ci) {
            if (cvalid[ci]) {
                const unsigned m1 = 1u << q[ci].x;
                const unsigned m2 = 1u << q[ci].y;
                const unsigned m3 = 1u << q[ci].z;
                const unsigned m4 = 1u << q[ci].w;
                const unsigned m0 = has_lo ? (1u << plo[ci]) : 0u;
                const unsigned m5 = has_hi ? (1u << phi[ci]) : 0u;
                const bool isC = (ci == 4);  // compile-time after unroll
                vmask[0] |= m0 | m2 | (isC ? 0u : m1);
                vmask[1] |= m1 | m3 | (isC ? 0u : m2);
                vmask[2] |= m2 | m4 | (isC ? 0u : m3);
                vmask[3] |= m3 | m5 | (isC ? 0u : m4);
            }
        }
        {
            // conv == 26 (all 26 neighbors exist, single label) -> clear bit
            const int nh = 3 - (h == 0) - (h == DIM - 1);
            const int nw = 3 - (w == 0) - (w == DIM - 1);
            const int ncols = nh * nw;
            const int nn0 = ncols * (has_lo ? 3 : 2) - 1;
            const int nn12 = ncols * 3 - 1;
            const int nn3 = ncols * (has_hi ? 3 : 2) - 1;
            if (nn0 == 26 && __popc(vmask[0]) == 1) vmask[0] = 0u;
            if (nn12 == 26 && __popc(vmask[1]) == 1) vmask[1] = 0u;
            if (nn12 == 26 && __popc(vmask[2]) == 1) vmask[2] = 0u;
            if (nn3 == 26 && __popc(vmask[3]) == 1) vmask[3] = 0u;
        }

        // ---------------- online exp sums, consumed in issue order ------------
        // kl_i = A_i/ET_i + log(ES_i) - log(ET_i)  (exact; logits ~N(0,1))
        float ES[VPT] = {0.f, 0.f, 0.f, 0.f};
        float ET[VPT] = {0.f, 0.f, 0.f, 0.f};
        float Aa[VPT] = {0.f, 0.f, 0.f, 0.f};
#pragma unroll
        for (int c = 0; c < NC; ++c) {
            const float4 s = sv[c];
            const float4 t = tv[c];
            { const float es = __expf(s.x), et = __expf(t.x);
              ES[0] += es; ET[0] += et; Aa[0] += et * (t.x - s.x); }
            { const float es = __expf(s.y), et = __expf(t.y);
              ES[1] += es; ET[1] += et; Aa[1] += et * (t.y - s.y); }
            { const float es = __expf(s.z), et = __expf(t.z);
              ES[2] += es; ET[2] += et; Aa[2] += et * (t.z - s.z); }
            { const float es = __expf(s.w), et = __expf(t.w);
              ES[3] += es; ET[3] += et; Aa[3] += et * (t.w - s.w); }
        }

#pragma unroll
        for (int i = 0; i < VPT; ++i) {
            const float kl = Aa[i] / ET[i] + __logf(ES[i]) - __logf(ET[i]);
            const unsigned m = vmask[i];
            // packed count update: word j += bit(2j) | bit(2j+1)<<16
            const unsigned long long y =
                (unsigned long long)m | ((unsigned long long)m << 15);
#pragma unroll
            for (int j = 0; j < 7; ++j) {
                cntpk[j] += (unsigned)((y >> (2 * j)) & 0x00010001ull);
            }
#pragma unroll
            for (int k = 0; k < NC; ++k) {
                if (m & (1u << k)) acc_sum[k] += kl;
            }
        }
    }

    // ---------------- block reduction: wave butterfly, then LDS combine -------
    __shared__ float lds_sum[4][NC];
    __shared__ unsigned lds_cnt[4][7];
    const int lane = tid & 63, wid = tid >> 6;
#pragma unroll
    for (int k = 0; k < NC; ++k) {
        float sv = acc_sum[k];
#pragma unroll
        for (int off = 32; off; off >>= 1) sv += __shfl_xor(sv, off);
        if (lane == 0) lds_sum[wid][k] = sv;
    }
#pragma unroll
    for (int j = 0; j < 7; ++j) {
        unsigned cv = cntpk[j];
#pragma unroll
        for (int off = 32; off; off >>= 1) cv += (unsigned)__shfl_xor((int)cv, off);
        if (lane == 0) lds_cnt[wid][j] = cv;
    }
    __syncthreads();
    if (tid < NC) {
        const float r = lds_sum[0][tid] + lds_sum[1][tid] + lds_sum[2][tid] + lds_sum[3][tid];
        partials[(b * NC + tid) * NBT + local] = r;
    } else if (tid < 2 * NC) {
        const int k = tid - NC;
        unsigned c = 0;
#pragma unroll
        for (int w = 0; w < 4; ++w)
            c += (lds_cnt[w][k >> 1] >> ((k & 1) * 16)) & 0xffffu;
        partials[(2 * NC + b * NC + k) * NBT + local] = (float)c;
    }
}

// 56 blocks x 64 threads: reduce one partials row each
__global__ __launch_bounds__(64) void bkd_reduce(const float* __restrict__ partials,
                                                 float* __restrict__ res) {
    const int p = blockIdx.x;
    const int lane = threadIdx.x;
    float acc = 0.f;
    for (int i = lane; i < NBT; i += 64) acc += partials[p * NBT + i];
#pragma unroll
    for (int off = 32; off; off >>= 1) acc += __shfl_xor(acc, off);
    if (lane == 0) res[p] = acc;
}

// single wave: combine 28 (sum,count) pairs into the scalar loss
__global__ __launch_bounds__(64) void bkd_last(const float* __restrict__ res,
                                               float* __restrict__ out) {
    const int j = threadIdx.x;
    float per = 0.f, valid = 0.f;
    if (j < 2 * NC) {
        const float nb = res[2 * NC + j];
        if (nb > 0.f) {
            per = res[j] / (NC * nb);
            valid = 1.f;
        }
    }
#pragma unroll
    for (int off = 32; off; off >>= 1) {
        per += __shfl_xor(per, off);
        valid += __shfl_xor(valid, off);
    }
    if (j == 0) out[0] = (valid > 0.f) ? (per / valid) : 0.f;
}

extern "C" void kernel_launch(void* const* d_in, const int* in_sizes, int n_in,
                              void* d_out, int out_size, void* d_ws, size_t ws_size,
                              hipStream_t stream) {
    const float* S = (const float*)d_in[0];
    const float* T = (const float*)d_in[1];
    const int* L = (const int*)d_in[2];
    float* out = (float*)d_out;
    float* partials = (float*)d_ws;            // 56 * 432 floats = 96,768 B
    float* res = partials + 4 * NC * NBT;      // 56 floats after partials

    bkd_main<<<dim3(2 * NBT), dim3(TPB), 0, stream>>>(S, T, L, partials);
    bkd_reduce<<<dim3(4 * NC), dim3(64), 0, stream>>>(partials, res);
    bkd_last<<<dim3(1), dim3(64), 0, stream>>>(res, out);
}

// Round 6
// 52.448 us; speedup vs baseline: 2.7252x; 2.7252x over previous
//
#include <hip/hip_runtime.h>

#define NC 14
#define DIM 96
#define VOL (96 * 96 * 96)   // 884736
#define VPT 4                 // voxels per thread
#define TPB 256
#define VPB (VPT * TPB)       // 1024
#define NBPB (VOL / VPB)      // 864 blocks per batch (exact)

__global__ __launch_bounds__(256, 2) void bkd_main(const float* __restrict__ S,
                                                   const float* __restrict__ T,
                                                   const int* __restrict__ L,
                                                   float* __restrict__ partials) {
    const int b = blockIdx.x / NBPB;
    const int local = blockIdx.x % NBPB;
    const int tid = threadIdx.x;
    const int v0 = local * VPB + tid * VPT;   // multiple of 4
    const int d0 = v0 % DIM;
    const int w = (v0 / DIM) % DIM;
    const int h = v0 / (DIM * DIM);

    const float* Sb = S + (size_t)b * NC * VOL + v0;
    const float* Tb = T + (size_t)b * NC * VOL + v0;
    const int* lab = L + b * VOL;

    // ---------------- issue LABEL loads first (consumed first) ----------------
    const bool has_lo = (d0 > 0);
    const bool has_hi = (d0 + VPT < DIM);
    int4 q[9];
    int plo[9], phi[9];
    bool cvalid[9];
#pragma unroll
    for (int dh = -1; dh <= 1; ++dh) {
#pragma unroll
        for (int dw = -1; dw <= 1; ++dw) {
            const int ci = (dh + 1) * 3 + (dw + 1);
            const int h2 = h + dh, w2 = w + dw;
            const bool ok = ((unsigned)h2 < DIM) & ((unsigned)w2 < DIM);
            cvalid[ci] = ok;
            const int* p = lab + (h2 * DIM + w2) * DIM + d0;
            if (ok) {
                q[ci] = *(const int4*)p;                       // labels d0..d0+3
                plo[ci] = has_lo ? p[-1] : 0;
                phi[ci] = has_hi ? p[4] : 0;
            }
        }
    }

    // ---------------- issue ALL 28 class float4 loads (stay in flight) --------
    float4 sv[NC], tv[NC];
#pragma unroll
    for (int c = 0; c < NC; ++c) {
        sv[c] = *(const float4*)(Sb + c * VOL);
        tv[c] = *(const float4*)(Tb + c * VOL);
    }

    // Fence: no VALU consumption may be hoisted above this point, no load sunk
    // below it -> all 55 loads are issued back-to-back, one latency exposure.
    __builtin_amdgcn_sched_barrier(0);

    // ---------------- boundary masks (VALU under class-load latency) ----------
    unsigned vmask[VPT] = {0u, 0u, 0u, 0u};
#pragma unroll
    for (int ci = 0; ci < 9; ++ci) {
        if (cvalid[ci]) {
            const unsigned m1 = 1u << q[ci].x;
            const unsigned m2 = 1u << q[ci].y;
            const unsigned m3 = 1u << q[ci].z;
            const unsigned m4 = 1u << q[ci].w;
            const unsigned m0 = has_lo ? (1u << plo[ci]) : 0u;
            const unsigned m5 = has_hi ? (1u << phi[ci]) : 0u;
            const bool isC = (ci == 4);                        // compile-time
            vmask[0] |= m0 | m2 | (isC ? 0u : m1);
            vmask[1] |= m1 | m3 | (isC ? 0u : m2);
            vmask[2] |= m2 | m4 | (isC ? 0u : m3);
            vmask[3] |= m3 | m5 | (isC ? 0u : m4);
        }
    }
    {
        // conv == 26 (all 26 neighbors exist, single label) -> clear that bit
        const int nh = 3 - (h == 0) - (h == DIM - 1);
        const int nw = 3 - (w == 0) - (w == DIM - 1);
        const int ncols = nh * nw;
        const int nn0 = ncols * (has_lo ? 3 : 2) - 1;
        const int nn12 = ncols * 3 - 1;
        const int nn3 = ncols * (has_hi ? 3 : 2) - 1;
        if (nn0 == 26 && __popc(vmask[0]) == 1) vmask[0] = 0u;
        if (nn12 == 26 && __popc(vmask[1]) == 1) vmask[1] = 0u;
        if (nn12 == 26 && __popc(vmask[2]) == 1) vmask[2] = 0u;
        if (nn3 == 26 && __popc(vmask[3]) == 1) vmask[3] = 0u;
    }

    // ---------------- online exp sums, consumed in issue order ----------------
    // kl_i = A_i/ET_i + log(ES_i) - log(ET_i)   (exact algebra; logits ~N(0,1))
    float ES[VPT] = {0.f, 0.f, 0.f, 0.f};
    float ET[VPT] = {0.f, 0.f, 0.f, 0.f};
    float Aa[VPT] = {0.f, 0.f, 0.f, 0.f};
#pragma unroll
    for (int c = 0; c < NC; ++c) {
        const float4 s = sv[c];
        const float4 t = tv[c];
        { const float es = __expf(s.x), et = __expf(t.x);
          ES[0] += es; ET[0] += et; Aa[0] += et * (t.x - s.x); }
        { const float es = __expf(s.y), et = __expf(t.y);
          ES[1] += es; ET[1] += et; Aa[1] += et * (t.y - s.y); }
        { const float es = __expf(s.z), et = __expf(t.z);
          ES[2] += es; ET[2] += et; Aa[2] += et * (t.z - s.z); }
        { const float es = __expf(s.w), et = __expf(t.w);
          ES[3] += es; ET[3] += et; Aa[3] += et * (t.w - s.w); }
    }

    float kl[VPT];
#pragma unroll
    for (int i = 0; i < VPT; ++i) {
        kl[i] = Aa[i] / ET[i] + __logf(ES[i]) - __logf(ET[i]);
    }

    // ---------------- masked per-class accumulation ----------------
    float acc_sum[NC];
    float acc_cnt[NC];
#pragma unroll
    for (int k = 0; k < NC; ++k) { acc_sum[k] = 0.f; acc_cnt[k] = 0.f; }
#pragma unroll
    for (int i = 0; i < VPT; ++i) {
#pragma unroll
        for (int k = 0; k < NC; ++k) {
            if (vmask[i] & (1u << k)) { acc_sum[k] += kl[i]; acc_cnt[k] += 1.f; }
        }
    }

    // ---------------- block reduction: wave shuffle, then LDS combine ---------
    __shared__ float lds[4][2 * NC];
    const int lane = tid & 63, wid = tid >> 6;
#pragma unroll
    for (int k = 0; k < NC; ++k) {
        float svv = acc_sum[k], cvv = acc_cnt[k];
#pragma unroll
        for (int off = 32; off; off >>= 1) {
            svv += __shfl_xor(svv, off);
            cvv += __shfl_xor(cvv, off);
        }
        if (lane == 0) { lds[wid][k] = svv; lds[wid][NC + k] = cvv; }
    }
    __syncthreads();
    if (tid < 2 * NC) {
        const float r = lds[0][tid] + lds[1][tid] + lds[2][tid] + lds[3][tid];
        const int k = (tid < NC) ? tid : (tid - NC);
        const int p = (tid < NC) ? (b * NC + k) : (2 * NC + b * NC + k);
        partials[p * NBPB + local] = r;
    }
}

// 56 blocks x 64 threads: reduce one partials row each
__global__ __launch_bounds__(64) void bkd_reduce(const float* __restrict__ partials,
                                                 float* __restrict__ res) {
    const int p = blockIdx.x;
    const int lane = threadIdx.x;
    float acc = 0.f;
    for (int i = lane; i < NBPB; i += 64) acc += partials[p * NBPB + i];
#pragma unroll
    for (int off = 32; off; off >>= 1) acc += __shfl_xor(acc, off);
    if (lane == 0) res[p] = acc;
}

// single wave: combine 28 (sum,count) pairs into the scalar loss
__global__ __launch_bounds__(64) void bkd_last(const float* __restrict__ res,
                                               float* __restrict__ out) {
    const int j = threadIdx.x;
    float per = 0.f, valid = 0.f;
    if (j < 2 * NC) {
        const float nb = res[2 * NC + j];
        if (nb > 0.f) {
            per = res[j] / (NC * nb);
            valid = 1.f;
        }
    }
#pragma unroll
    for (int off = 32; off; off >>= 1) {
        per += __shfl_xor(per, off);
        valid += __shfl_xor(valid, off);
    }
    if (j == 0) out[0] = (valid > 0.f) ? (per / valid) : 0.f;
}

extern "C" void kernel_launch(void* const* d_in, const int* in_sizes, int n_in,
                              void* d_out, int out_size, void* d_ws, size_t ws_size,
                              hipStream_t stream) {
    const float* S = (const float*)d_in[0];
    const float* T = (const float*)d_in[1];
    const int* L = (const int*)d_in[2];
    float* out = (float*)d_out;
    float* partials = (float*)d_ws;                 // 56 * 864 floats = 193,536 B
    float* res = partials + 2 * NC * 2 * NBPB;      // 56 floats after partials

    bkd_main<<<dim3(2 * NBPB), dim3(TPB), 0, stream>>>(S, T, L, partials);
    bkd_reduce<<<dim3(4 * NC), dim3(64), 0, stream>>>(partials, res);
    bkd_last<<<dim3(1), dim3(64), 0, stream>>>(res, out);
}